// Round 4
// baseline (192.880 us; speedup 1.0000x reference)
//
#include <hip/hip_runtime.h>
#include <stdint.h>

#define ALPHA 0.2f
#define LOG2E 1.4426950408889634f

typedef __attribute__((ext_vector_type(8))) short short8;
typedef __attribute__((ext_vector_type(4))) float f32x4;
typedef __attribute__((ext_vector_type(16))) float f32x16;
typedef __attribute__((ext_vector_type(4))) int int4v;
typedef __attribute__((ext_vector_type(2))) unsigned int uint2v;

#if __has_builtin(__builtin_amdgcn_exp2f)
#define EXP2(x) __builtin_amdgcn_exp2f(x)
#else
#define EXP2(x) exp2f(x)
#endif

__device__ __forceinline__ unsigned short f2bf(float x){
  union { float f; uint32_t u; } v; v.f = x;
  uint32_t u = v.u;
  u += 0x7FFFu + ((u >> 16) & 1u);
  return (unsigned short)(u >> 16);
}
__device__ __forceinline__ float bf2f(unsigned short s){
  union { uint32_t u; float f; } v; v.u = ((uint32_t)s) << 16; return v.f;
}
// order-preserving f32 <-> u32 (for atomicMax); 0 is below every real encoding
__device__ __forceinline__ unsigned encf(float x){
  unsigned u = __float_as_uint(x);
  return (u & 0x80000000u) ? ~u : (u | 0x80000000u);
}
__device__ __forceinline__ float decf(unsigned u){
  return (u & 0x80000000u) ? __uint_as_float(u & 0x7FFFFFFFu) : __uint_as_float(~u);
}

// ---- hamilton^T as bf16 hi/lo planes + zero the tiny accumulators ----
__global__ void k_ham(const float* __restrict__ W, unsigned short* __restrict__ hi,
                      unsigned short* __restrict__ lo, unsigned* __restrict__ S2enc,
                      float* __restrict__ gsum, float* __restrict__ gsumsq){
  if (blockIdx.x == 0){
    if (threadIdx.x == 0) S2enc[0] = 0u;
    gsum[threadIdx.x] = 0.f; gsumsq[threadIdx.x] = 0.f;
  }
  int id = blockIdx.x * 256 + threadIdx.x;   // id = c*1024 + k
  int c = id >> 10, k = id & 1023;
  int b = k >> 8, r = k & 255;
  int cb = c >> 6, col = c & 63;
  const int   comp[4][4] = {{0,1,2,3},{1,0,3,2},{2,3,0,1},{3,2,1,0}};
  const float sgn [4][4] = {{1.f,-1.f,-1.f,-1.f},{1.f,1.f,-1.f,1.f},
                            {1.f,1.f,1.f,-1.f},{1.f,-1.f,1.f,1.f}};
  float v = sgn[b][cb] * W[r * 256 + comp[b][cb] * 64 + col];
  unsigned short h = f2bf(v);
  hi[id] = h;
  lo[id] = f2bf(v - bf2f(h));
}

// ---- GEMM1: h = input @ hamilton (hi/lo split => ~fp32 accuracy)
// writes h^T bf16 (XOR-swizzled) + s1s/s2s (scaled by log2e) + global max(s2s)
__global__ __launch_bounds__(256) void k_gemm1(
    const float* __restrict__ inp, const unsigned short* __restrict__ hamHi,
    const unsigned short* __restrict__ hamLo, const float* __restrict__ avec,
    unsigned short* __restrict__ hT, float* __restrict__ s1s, float* __restrict__ s2s,
    unsigned* __restrict__ S2enc){
  int i0 = blockIdx.x * 32;
  int w = threadIdx.x >> 6, lane = threadIdx.x & 63;
  int mi = lane & 15, g = lane >> 4;
  int cbase = w * 64;
  f32x4 acc[2][4];
#pragma unroll
  for (int mf=0; mf<2; ++mf)
#pragma unroll
    for (int nf=0; nf<4; ++nf) acc[mf][nf] = (f32x4){0.f,0.f,0.f,0.f};

  for (int k0 = 0; k0 < 1024; k0 += 32){
    short8 ah[2], al[2];
#pragma unroll
    for (int mf=0; mf<2; ++mf){
      const float* ap = inp + (size_t)(i0 + 16*mf + mi) * 1024 + k0 + 8*g;
      f32x4 x0 = *(const f32x4*)ap;
      f32x4 x1 = *(const f32x4*)(ap + 4);
#pragma unroll
      for (int e=0; e<8; ++e){
        float x = (e < 4) ? x0[e] : x1[e-4];
        unsigned short h = f2bf(x);
        ah[mf][e] = (short)h;
        al[mf][e] = (short)f2bf(x - bf2f(h));
      }
    }
    short8 bh[4], bl[4];
#pragma unroll
    for (int nf=0; nf<4; ++nf){
      size_t off = (size_t)(cbase + 16*nf + mi) * 1024 + k0 + 8*g;
      bh[nf] = *(const short8*)(hamHi + off);
      bl[nf] = *(const short8*)(hamLo + off);
    }
#pragma unroll
    for (int mf=0; mf<2; ++mf)
#pragma unroll
      for (int nf=0; nf<4; ++nf){
        acc[mf][nf] = __builtin_amdgcn_mfma_f32_16x16x32_bf16(ah[mf], bh[nf], acc[mf][nf], 0,0,0);
        acc[mf][nf] = __builtin_amdgcn_mfma_f32_16x16x32_bf16(ah[mf], bl[nf], acc[mf][nf], 0,0,0);
        acc[mf][nf] = __builtin_amdgcn_mfma_f32_16x16x32_bf16(al[mf], bh[nf], acc[mf][nf], 0,0,0);
      }
  }
  float p1[2][4] = {{0,0,0,0},{0,0,0,0}}, p2[2][4] = {{0,0,0,0},{0,0,0,0}};
#pragma unroll
  for (int nf=0; nf<4; ++nf){
    int c = cbase + 16*nf + mi;
    float a1c = avec[c], a2c = avec[256 + c];
    int Sc = (c & 7) << 3;
#pragma unroll
    for (int mf=0; mf<2; ++mf){
      int ibase = i0 + 16*mf + 4*g;
      uint2v u;
      u[0] = (uint32_t)f2bf(acc[mf][nf][0]) | ((uint32_t)f2bf(acc[mf][nf][1]) << 16);
      u[1] = (uint32_t)f2bf(acc[mf][nf][2]) | ((uint32_t)f2bf(acc[mf][nf][3]) << 16);
      *(uint2v*)(hT + (size_t)c * 8192 + (size_t)(ibase ^ Sc)) = u;
#pragma unroll
      for (int rg=0; rg<4; ++rg){
        p1[mf][rg] += acc[mf][nf][rg] * a1c;
        p2[mf][rg] += acc[mf][nf][rg] * a2c;
      }
    }
  }
#pragma unroll
  for (int off=1; off<16; off<<=1){
#pragma unroll
    for (int mf=0; mf<2; ++mf)
#pragma unroll
      for (int rg=0; rg<4; ++rg){
        p1[mf][rg] += __shfl_xor(p1[mf][rg], off);
        p2[mf][rg] += __shfl_xor(p2[mf][rg], off);
      }
  }
  __shared__ float red1[4][32], red2[4][32];
  if (mi == 0){
#pragma unroll
    for (int mf=0; mf<2; ++mf)
#pragma unroll
      for (int rg=0; rg<4; ++rg){
        red1[w][16*mf + 4*g + rg] = p1[mf][rg];
        red2[w][16*mf + 4*g + rg] = p2[mf][rg];
      }
  }
  __syncthreads();
  if (threadIdx.x < 32){
    int r = threadIdx.x;
    float v1 = red1[0][r] + red1[1][r] + red1[2][r] + red1[3][r];
    float v2 = red2[0][r] + red2[1][r] + red2[2][r] + red2[3][r];
    s1s[i0 + r] = v1 * LOG2E;
    float v2s = v2 * LOG2E;
    s2s[i0 + r] = v2s;
    float m = v2s;
#pragma unroll
    for (int off=1; off<32; off<<=1) m = fmaxf(m, __shfl_xor(m, off));
    if (r == 0) atomicMax(S2enc, encf(m));
  }
}

// stage hT tile t (256c x 64j, 32KB) into hbuf[b]; linear LDS dest = lane*16B
#define STAGE(t, b) do { \
    _Pragma("unroll") \
    for (int r_ = 0; r_ < 8; ++r_){ \
      int ch_ = tid + r_*256; \
      const unsigned short* gp_ = hT + (size_t)(ch_ >> 3)*8192 + jw0 + (t)*64 + (ch_&7)*8; \
      __builtin_amdgcn_global_load_lds((const __attribute__((address_space(1))) void*)(const void*)gp_, \
          (__attribute__((address_space(3))) void*)(void*)&hbuf[(b)][ch_*8], 16, 0, 0); \
    } } while(0)

// load adj regs for tile t: per lane row (i0w+r31), j = t*64 + ks*16 + hi*8 + e
#define ALOAD(dst, t) do { \
    _Pragma("unroll") \
    for (int ks_ = 0; ks_ < 4; ++ks_){ \
      dst[2*ks_]   = *(const int4v*)(arow + (t)*64 + ks_*16); \
      dst[2*ks_+1] = *(const int4v*)(arow + (t)*64 + ks_*16 + 4); \
    } } while(0)

// ---- fused: stream adj once + masked-softmax + P@h via 32x32x16 MFMA ----
__global__ __launch_bounds__(256,1) void k_attn(
    const int* __restrict__ adj, const unsigned short* __restrict__ hT,
    const float* __restrict__ s1s, const float* __restrict__ s2s,
    const unsigned* __restrict__ S2enc, float* __restrict__ accp, float* __restrict__ Zp){
  __shared__ unsigned short hbuf[2][256*64];   // 64 KB double-buffered h^T tiles
  __shared__ float s2l[2048];                  // 8 KB s2 slice
  const int tid = threadIdx.x;
  const int id = blockIdx.x;
  // XCD swizzle: each XCD owns one js slice (its 1MB hT slice stays L2-hot)
  const int js = (id & 7) >> 1;
  const int rb = ((id >> 3) << 1) | (id & 1);
  const int w = tid >> 6, lane = tid & 63;
  const int r31 = lane & 31, hi = lane >> 5;
  const int i0w = rb * 128 + w * 32;           // wave owns 32 rows
  const int jw0 = js * 2048;

  { f32x4 v0 = *(const f32x4*)(s2s + jw0 + tid*8);
    f32x4 v1 = *(const f32x4*)(s2s + jw0 + tid*8 + 4);
    *(f32x4*)&s2l[tid*8] = v0; *(f32x4*)&s2l[tid*8 + 4] = v1; }

  const float S2MAX = decf(S2enc[0]);
  const float s1v = s1s[i0w + r31];
  const float xm = s1v + S2MAX;
  const float m2 = fmaxf(xm, ALPHA * xm);      // scaled lrelu of the global bound
  const float P1 = s1v - m2;
  const float P2 = ALPHA * s1v - m2;

  const int* arow = adj + (size_t)(i0w + r31) * 8192 + jw0 + hi*8;

  f32x16 acc[8];
#pragma unroll
  for (int nf=0; nf<8; ++nf)
#pragma unroll
    for (int q=0; q<16; ++q) acc[nf][q] = 0.f;
  float zac = 0.f;

  int4v cur[8], nxt[8];
  ALOAD(cur, 0);
  STAGE(0, 0);
  __syncthreads();

  for (int tile = 0; tile < 32; ++tile){
    const int buf = tile & 1;
    if (tile < 31){
      STAGE(tile + 1, buf ^ 1);
      ALOAD(nxt, tile + 1);
    }
#pragma unroll
    for (int ks=0; ks<4; ++ks){
      f32x4 sa = *(const f32x4*)&s2l[tile*64 + ks*16 + hi*8];
      f32x4 sb = *(const f32x4*)&s2l[tile*64 + ks*16 + hi*8 + 4];
      short8 pa;
#pragma unroll
      for (int e=0; e<8; ++e){
        float s2e = (e < 4) ? sa[e] : sb[e-4];
        float t1 = P1 + s2e;
        float t2 = fmaf(ALPHA, s2e, P2);
        float pe = EXP2(fmaxf(t1, t2));
        int ae = (e < 4) ? cur[2*ks][e] : cur[2*ks+1][e-4];
        pe = (ae > 0) ? pe : 0.f;
        zac += pe;
        pa[e] = (short)f2bf(pe);
      }
      const int xk = ks*16 + hi*8;
#pragma unroll
      for (int nf=0; nf<8; ++nf){
        const int c = 32*nf + r31;
        short8 b = *(const short8*)&hbuf[buf][c*64 + (xk ^ ((c&7)<<3))];
        acc[nf] = __builtin_amdgcn_mfma_f32_32x32x16_bf16(pa, b, acc[nf], 0,0,0);
      }
    }
    if (tile < 31){
#pragma unroll
      for (int q=0; q<8; ++q) cur[q] = nxt[q];
    }
    __syncthreads();
  }
  // Z: combine the two k-halves (hi lanes) -> one slot per row
  zac += __shfl_xor(zac, 32);
  if (lane < 32) Zp[js*8192 + i0w + lane] = zac;
  // unnormalized h' partial: unique (js,row,c) slots, plain stores
#pragma unroll
  for (int nf=0; nf<8; ++nf){
    const int c = 32*nf + r31;
#pragma unroll
    for (int reg=0; reg<16; ++reg){
      const int roff = (reg&3) + 8*(reg>>2) + 4*hi;
      accp[(size_t)(js*8192 + i0w + roff)*256 + c] = acc[nf][reg];
    }
  }
}

// ---- reduce 4 partials, normalize by Z, write h', accumulate column stats ----
__global__ void k_stats(const float* __restrict__ accp, const float* __restrict__ Zp,
                        float* __restrict__ hp, float* __restrict__ gsum,
                        float* __restrict__ gsumsq){
  int c = threadIdx.x;
  int r0 = blockIdx.x * 32;
  float s = 0.f, sq = 0.f;
  for (int r=0; r<32; ++r){
    int i = r0 + r;
    float z = Zp[i] + Zp[8192 + i] + Zp[16384 + i] + Zp[24576 + i];
    float inv = (z > 0.f) ? 1.f / z : 0.f;
    size_t o = (size_t)i * 256 + c;
    float v = (accp[o] + accp[o + 8192*256] + accp[o + 2*8192*256] + accp[o + 3*8192*256]) * inv;
    hp[o] = v;
    s += v; sq += v*v;
  }
  atomicAdd(&gsum[c], s);
  atomicAdd(&gsumsq[c], sq);
}

// ---- batchnorm + elu, in-place on d_out ----
__global__ void k_bnelu(float* __restrict__ out, const float* __restrict__ gsum,
                        const float* __restrict__ gsumsq, const float* __restrict__ gamma,
                        const float* __restrict__ beta){
  int id = blockIdx.x * 256 + threadIdx.x;
  int c = id & 255;
  float mean = gsum[c] * (1.f/8192.f);
  float var  = gsumsq[c] * (1.f/8192.f) - mean*mean;
  float x = (out[id] - mean) * rsqrtf(var + 1e-5f) * gamma[c] + beta[c];
  out[id] = x > 0.f ? x : (EXP2(x * LOG2E) - 1.f);
}

extern "C" void kernel_launch(void* const* d_in, const int* in_sizes, int n_in,
                              void* d_out, int out_size, void* d_ws, size_t ws_size,
                              hipStream_t stream){
  const float* inp   = (const float*)d_in[0];
  const int*   adj   = (const int*)d_in[1];
  const float* W     = (const float*)d_in[2];
  const float* avec  = (const float*)d_in[3];
  const float* gamma = (const float*)d_in[4];
  const float* beta  = (const float*)d_in[5];
  float* out = (float*)d_out;

  char* ws = (char*)d_ws;
  float* accp = (float*)ws;                               // 4*8192*256 f = 32 MB
  float* Zp   = accp + 4*8192*256;                        // 32768 f
  unsigned short* hamHi = (unsigned short*)(Zp + 32768);  // 262144 bf16
  unsigned short* hamLo = hamHi + 262144;
  unsigned short* hT    = hamLo + 262144;                 // 2097152 bf16
  float* s1s = (float*)(hT + 2097152);
  float* s2s = s1s + 8192;
  unsigned* S2enc = (unsigned*)(s2s + 8192);
  float* gsum   = (float*)(S2enc + 64);
  float* gsumsq = gsum + 256;

  k_ham<<<1024, 256, 0, stream>>>(W, hamHi, hamLo, S2enc, gsum, gsumsq);
  k_gemm1<<<256, 256, 0, stream>>>(inp, hamHi, hamLo, avec, hT, s1s, s2s, S2enc);
  k_attn<<<256, 256, 0, stream>>>(adj, hT, s1s, s2s, S2enc, accp, Zp);
  k_stats<<<256, 256, 0, stream>>>(accp, Zp, out, gsum, gsumsq);
  k_bnelu<<<8192, 256, 0, stream>>>(out, gsum, gsumsq, gamma, beta);
}

// Round 5
// 177.265 us; speedup vs baseline: 1.0881x; 1.0881x over previous
//
#include <hip/hip_runtime.h>
#include <stdint.h>

#define ALPHA 0.2f
#define LOG2E 1.4426950408889634f

typedef __attribute__((ext_vector_type(8))) short short8;
typedef __attribute__((ext_vector_type(4))) float f32x4;
typedef __attribute__((ext_vector_type(16))) float f32x16;
typedef __attribute__((ext_vector_type(4))) int int4v;
typedef __attribute__((ext_vector_type(2))) unsigned int uint2v;

#if __has_builtin(__builtin_amdgcn_exp2f)
#define EXP2(x) __builtin_amdgcn_exp2f(x)
#else
#define EXP2(x) exp2f(x)
#endif

__device__ __forceinline__ unsigned short f2bf(float x){
  union { float f; uint32_t u; } v; v.f = x;
  uint32_t u = v.u;
  u += 0x7FFFu + ((u >> 16) & 1u);
  return (unsigned short)(u >> 16);
}
__device__ __forceinline__ float bf2f(unsigned short s){
  union { uint32_t u; float f; } v; v.u = ((uint32_t)s) << 16; return v.f;
}
// order-preserving f32 <-> u32 (for atomicMax); 0 is below every real encoding
__device__ __forceinline__ unsigned encf(float x){
  unsigned u = __float_as_uint(x);
  return (u & 0x80000000u) ? ~u : (u | 0x80000000u);
}
__device__ __forceinline__ float decf(unsigned u){
  return (u & 0x80000000u) ? __uint_as_float(u & 0x7FFFFFFFu) : __uint_as_float(~u);
}

// ---- hamilton^T as bf16 hi/lo planes + zero the tiny accumulators ----
__global__ void k_ham(const float* __restrict__ W, unsigned short* __restrict__ hi,
                      unsigned short* __restrict__ lo, unsigned* __restrict__ S2enc,
                      float* __restrict__ gsum, float* __restrict__ gsumsq){
  if (blockIdx.x == 0){
    if (threadIdx.x == 0) S2enc[0] = 0u;
    gsum[threadIdx.x] = 0.f; gsumsq[threadIdx.x] = 0.f;
  }
  int id = blockIdx.x * 256 + threadIdx.x;   // id = c*1024 + k
  int c = id >> 10, k = id & 1023;
  int b = k >> 8, r = k & 255;
  int cb = c >> 6, col = c & 63;
  const int   comp[4][4] = {{0,1,2,3},{1,0,3,2},{2,3,0,1},{3,2,1,0}};
  const float sgn [4][4] = {{1.f,-1.f,-1.f,-1.f},{1.f,1.f,-1.f,1.f},
                            {1.f,1.f,1.f,-1.f},{1.f,-1.f,1.f,1.f}};
  float v = sgn[b][cb] * W[r * 256 + comp[b][cb] * 64 + col];
  unsigned short h = f2bf(v);
  hi[id] = h;
  lo[id] = f2bf(v - bf2f(h));
}

// ---- fused: blocks 0..255 = GEMM1 (h = input@hamilton, fp32-split);
//             blocks 256..16639 = adj bitmask pack (independent -> overlaps) ----
// pack layout: word[row*128 + (j>>8)*4 + (j&3)], bit ((j>>2)&63)
__global__ __launch_bounds__(256) void k_work(
    const float* __restrict__ inp, const int* __restrict__ adj,
    const unsigned short* __restrict__ hamHi, const unsigned short* __restrict__ hamLo,
    const float* __restrict__ avec, unsigned short* __restrict__ hT,
    float* __restrict__ s1s, float* __restrict__ s2s, unsigned* __restrict__ S2enc,
    unsigned long long* __restrict__ bm){
  if (blockIdx.x >= 256){
    // ---------------- pack body (streams adj at full BW) ----------------
    const int lane = threadIdx.x & 63;
    const size_t wid = ((size_t)(blockIdx.x - 256) * 256 + threadIdx.x) >> 6;
    const size_t W0 = wid * 1024;              // 1024 consecutive elems per wave
    unsigned long long b[16];
#pragma unroll
    for (int q = 0; q < 4; ++q){
      int4v a = *(const int4v*)(adj + W0 + 256*q + 4*lane);
#pragma unroll
      for (int k = 0; k < 4; ++k) b[4*q + k] = __ballot(a[k] > 0);
    }
    if (lane < 16){
      unsigned long long v = b[0];
#pragma unroll
      for (int m = 1; m < 16; ++m) v = (lane == m) ? b[m] : v;
      bm[W0/64 + lane] = v;
    }
    return;
  }
  // ---------------- gemm1 body ----------------
  int i0 = blockIdx.x * 32;
  int w = threadIdx.x >> 6, lane = threadIdx.x & 63;
  int mi = lane & 15, g = lane >> 4;
  int cbase = w * 64;
  f32x4 acc[2][4];
#pragma unroll
  for (int mf=0; mf<2; ++mf)
#pragma unroll
    for (int nf=0; nf<4; ++nf) acc[mf][nf] = (f32x4){0.f,0.f,0.f,0.f};

  for (int k0 = 0; k0 < 1024; k0 += 32){
    short8 ah[2], al[2];
#pragma unroll
    for (int mf=0; mf<2; ++mf){
      const float* ap = inp + (size_t)(i0 + 16*mf + mi) * 1024 + k0 + 8*g;
      f32x4 x0 = *(const f32x4*)ap;
      f32x4 x1 = *(const f32x4*)(ap + 4);
#pragma unroll
      for (int e=0; e<8; ++e){
        float x = (e < 4) ? x0[e] : x1[e-4];
        unsigned short h = f2bf(x);
        ah[mf][e] = (short)h;
        al[mf][e] = (short)f2bf(x - bf2f(h));
      }
    }
    short8 bh[4], bl[4];
#pragma unroll
    for (int nf=0; nf<4; ++nf){
      size_t off = (size_t)(cbase + 16*nf + mi) * 1024 + k0 + 8*g;
      bh[nf] = *(const short8*)(hamHi + off);
      bl[nf] = *(const short8*)(hamLo + off);
    }
#pragma unroll
    for (int mf=0; mf<2; ++mf)
#pragma unroll
      for (int nf=0; nf<4; ++nf){
        acc[mf][nf] = __builtin_amdgcn_mfma_f32_16x16x32_bf16(ah[mf], bh[nf], acc[mf][nf], 0,0,0);
        acc[mf][nf] = __builtin_amdgcn_mfma_f32_16x16x32_bf16(ah[mf], bl[nf], acc[mf][nf], 0,0,0);
        acc[mf][nf] = __builtin_amdgcn_mfma_f32_16x16x32_bf16(al[mf], bh[nf], acc[mf][nf], 0,0,0);
      }
  }
  float p1[2][4] = {{0,0,0,0},{0,0,0,0}}, p2[2][4] = {{0,0,0,0},{0,0,0,0}};
#pragma unroll
  for (int nf=0; nf<4; ++nf){
    int c = cbase + 16*nf + mi;
    float a1c = avec[c], a2c = avec[256 + c];
    int Sc = (c & 7) << 3;
#pragma unroll
    for (int mf=0; mf<2; ++mf){
      int ibase = i0 + 16*mf + 4*g;
      uint2v u;
      u[0] = (uint32_t)f2bf(acc[mf][nf][0]) | ((uint32_t)f2bf(acc[mf][nf][1]) << 16);
      u[1] = (uint32_t)f2bf(acc[mf][nf][2]) | ((uint32_t)f2bf(acc[mf][nf][3]) << 16);
      *(uint2v*)(hT + (size_t)c * 8192 + (size_t)(ibase ^ Sc)) = u;
#pragma unroll
      for (int rg=0; rg<4; ++rg){
        p1[mf][rg] += acc[mf][nf][rg] * a1c;
        p2[mf][rg] += acc[mf][nf][rg] * a2c;
      }
    }
  }
#pragma unroll
  for (int off=1; off<16; off<<=1){
#pragma unroll
    for (int mf=0; mf<2; ++mf)
#pragma unroll
      for (int rg=0; rg<4; ++rg){
        p1[mf][rg] += __shfl_xor(p1[mf][rg], off);
        p2[mf][rg] += __shfl_xor(p2[mf][rg], off);
      }
  }
  __shared__ float red1[4][32], red2[4][32];
  if (mi == 0){
#pragma unroll
    for (int mf=0; mf<2; ++mf)
#pragma unroll
      for (int rg=0; rg<4; ++rg){
        red1[w][16*mf + 4*g + rg] = p1[mf][rg];
        red2[w][16*mf + 4*g + rg] = p2[mf][rg];
      }
  }
  __syncthreads();
  if (threadIdx.x < 32){
    int r = threadIdx.x;
    float v1 = red1[0][r] + red1[1][r] + red1[2][r] + red1[3][r];
    float v2 = red2[0][r] + red2[1][r] + red2[2][r] + red2[3][r];
    s1s[i0 + r] = v1 * LOG2E;
    float v2s = v2 * LOG2E;
    s2s[i0 + r] = v2s;
    float m = v2s;
#pragma unroll
    for (int off=1; off<32; off<<=1) m = fmaxf(m, __shfl_xor(m, off));
    if (r == 0) atomicMax(S2enc, encf(m));
  }
}

// stage hT tile t (256c x 64j, 32KB) into hbuf[b]; linear LDS dest = lane*16B
#define STAGE(t, b) do { \
    _Pragma("unroll") \
    for (int r_ = 0; r_ < 8; ++r_){ \
      int ch_ = tid + r_*256; \
      const unsigned short* gp_ = hT + (size_t)(ch_ >> 3)*8192 + jw0 + (t)*64 + (ch_&7)*8; \
      __builtin_amdgcn_global_load_lds((const __attribute__((address_space(1))) void*)(const void*)gp_, \
          (__attribute__((address_space(3))) void*)(void*)&hbuf[(b)][ch_*8], 16, 0, 0); \
    } } while(0)

// ---- fused masked-softmax @ h : bm-masked, 32x32x16 MFMA, no atomics ----
__global__ __launch_bounds__(256,1) void k_attn(
    const unsigned long long* __restrict__ bm, const unsigned short* __restrict__ hT,
    const float* __restrict__ s1s, const float* __restrict__ s2s,
    const unsigned* __restrict__ S2enc, float* __restrict__ accp, float* __restrict__ Zp){
  __shared__ unsigned short hbuf[2][256*64];   // 64 KB double-buffered h^T tiles
  __shared__ float s2l[2048];                  // 8 KB s2 slice
  const int tid = threadIdx.x;
  const int id = blockIdx.x;
  // XCD swizzle: each XCD pair owns one js slice (its 1MB hT slice stays L2-hot)
  const int js = (id & 7) >> 1;
  const int rb = ((id >> 3) << 1) | (id & 1);
  const int w = tid >> 6, lane = tid & 63;
  const int r31 = lane & 31, hi = lane >> 5;
  const int i0w = rb * 128 + w * 32;           // wave owns 32 rows
  const int jw0 = js * 2048;

  { f32x4 v0 = *(const f32x4*)(s2s + jw0 + tid*8);
    f32x4 v1 = *(const f32x4*)(s2s + jw0 + tid*8 + 4);
    *(f32x4*)&s2l[tid*8] = v0; *(f32x4*)&s2l[tid*8 + 4] = v1; }

  const float S2MAX = decf(S2enc[0]);
  const float s1v = s1s[i0w + r31];
  const float xm = s1v + S2MAX;
  const float m2 = fmaxf(xm, ALPHA * xm);      // scaled lrelu of the global bound
  const float P1 = s1v - m2;
  const float P2 = ALPHA * s1v - m2;

  // bm words for this row & js slice: 32 words; groups of 4 per 4 tiles
  const unsigned long long* brow = bm + (size_t)(i0w + r31) * 128 + js * 32;

  f32x16 acc[8];
#pragma unroll
  for (int nf=0; nf<8; ++nf)
#pragma unroll
    for (int q=0; q<16; ++q) acc[nf][q] = 0.f;
  float zac = 0.f;

  unsigned long long Wc[4], Wn[4];
#pragma unroll
  for (int k=0;k<4;++k) Wc[k] = brow[k];
  STAGE(0, 0);
  __syncthreads();

  for (int tile = 0; tile < 32; ++tile){
    const int buf = tile & 1;
    if ((tile & 3) == 0){
      if (tile){
#pragma unroll
        for (int k=0;k<4;++k) Wc[k] = Wn[k];
      }
      if (tile + 4 < 32){
        const unsigned long long* p = brow + (tile >> 2)*4 + 4;
#pragma unroll
        for (int k=0;k<4;++k) Wn[k] = p[k];
      }
    }
    if (tile < 31) STAGE(tile + 1, buf ^ 1);
#pragma unroll
    for (int ks=0; ks<4; ++ks){
      f32x4 sa = *(const f32x4*)&s2l[tile*64 + ks*16 + hi*8];
      f32x4 sb = *(const f32x4*)&s2l[tile*64 + ks*16 + hi*8 + 4];
      const int sh0 = ((tile & 3) << 4) + (ks << 2) + (hi << 1);
      unsigned tt[4];
#pragma unroll
      for (int k=0;k<4;++k) tt[k] = (unsigned)(Wc[k] >> sh0);
      short8 pa;
#pragma unroll
      for (int e=0; e<8; ++e){
        float s2e = (e < 4) ? sa[e] : sb[e-4];
        float t1 = P1 + s2e;
        float t2 = fmaf(ALPHA, s2e, P2);
        float pe = EXP2(fmaxf(t1, t2));
        pe = ((tt[e & 3] >> (e >> 2)) & 1u) ? pe : 0.f;
        zac += pe;
        pa[e] = (short)f2bf(pe);
      }
      const int xk = ks*16 + hi*8;
#pragma unroll
      for (int nf=0; nf<8; ++nf){
        const int c = 32*nf + r31;
        short8 b = *(const short8*)&hbuf[buf][c*64 + (xk ^ ((c&7)<<3))];
        acc[nf] = __builtin_amdgcn_mfma_f32_32x32x16_bf16(pa, b, acc[nf], 0,0,0);
      }
    }
    __syncthreads();
  }
  // Z: combine the two k-halves (hi lanes) -> one slot per row
  zac += __shfl_xor(zac, 32);
  if (lane < 32) Zp[js*8192 + i0w + lane] = zac;
  // unnormalized h' partial: unique (js,row,c) slots, plain stores
#pragma unroll
  for (int nf=0; nf<8; ++nf){
    const int c = 32*nf + r31;
#pragma unroll
    for (int reg=0; reg<16; ++reg){
      const int roff = (reg&3) + 8*(reg>>2) + 4*hi;
      accp[(size_t)(js*8192 + i0w + roff)*256 + c] = acc[nf][reg];
    }
  }
}

// ---- reduce 4 partials, normalize by Z, write h', accumulate column stats ----
__global__ void k_stats(const float* __restrict__ accp, const float* __restrict__ Zp,
                        float* __restrict__ hp, float* __restrict__ gsum,
                        float* __restrict__ gsumsq){
  int c = threadIdx.x;
  int r0 = blockIdx.x * 32;
  float s = 0.f, sq = 0.f;
  for (int r=0; r<32; ++r){
    int i = r0 + r;
    float z = Zp[i] + Zp[8192 + i] + Zp[16384 + i] + Zp[24576 + i];
    float inv = (z > 0.f) ? 1.f / z : 0.f;
    size_t o = (size_t)i * 256 + c;
    float v = (accp[o] + accp[o + 8192*256] + accp[o + 2*8192*256] + accp[o + 3*8192*256]) * inv;
    hp[o] = v;
    s += v; sq += v*v;
  }
  atomicAdd(&gsum[c], s);
  atomicAdd(&gsumsq[c], sq);
}

// ---- batchnorm + elu, in-place on d_out ----
__global__ void k_bnelu(float* __restrict__ out, const float* __restrict__ gsum,
                        const float* __restrict__ gsumsq, const float* __restrict__ gamma,
                        const float* __restrict__ beta){
  int id = blockIdx.x * 256 + threadIdx.x;
  int c = id & 255;
  float mean = gsum[c] * (1.f/8192.f);
  float var  = gsumsq[c] * (1.f/8192.f) - mean*mean;
  float x = (out[id] - mean) * rsqrtf(var + 1e-5f) * gamma[c] + beta[c];
  out[id] = x > 0.f ? x : (EXP2(x * LOG2E) - 1.f);
}

extern "C" void kernel_launch(void* const* d_in, const int* in_sizes, int n_in,
                              void* d_out, int out_size, void* d_ws, size_t ws_size,
                              hipStream_t stream){
  const float* inp   = (const float*)d_in[0];
  const int*   adj   = (const int*)d_in[1];
  const float* W     = (const float*)d_in[2];
  const float* avec  = (const float*)d_in[3];
  const float* gamma = (const float*)d_in[4];
  const float* beta  = (const float*)d_in[5];
  float* out = (float*)d_out;

  char* ws = (char*)d_ws;
  float* accp = (float*)ws;                               // 4*8192*256 f = 32 MB
  float* Zp   = accp + 4*8192*256;                        // 32768 f
  unsigned short* hamHi = (unsigned short*)(Zp + 32768);  // 262144 bf16
  unsigned short* hamLo = hamHi + 262144;
  unsigned short* hT    = hamLo + 262144;                 // 2097152 bf16
  float* s1s = (float*)(hT + 2097152);
  float* s2s = s1s + 8192;
  unsigned* S2enc = (unsigned*)(s2s + 8192);
  float* gsum   = (float*)(S2enc + 64);
  float* gsumsq = gsum + 256;
  unsigned long long* bm = (unsigned long long*)(gsumsq + 256);  // 1M u64 = 8MB

  k_ham<<<1024, 256, 0, stream>>>(W, hamHi, hamLo, S2enc, gsum, gsumsq);
  k_work<<<16640, 256, 0, stream>>>(inp, adj, hamHi, hamLo, avec, hT, s1s, s2s, S2enc, bm);
  k_attn<<<256, 256, 0, stream>>>(bm, hT, s1s, s2s, S2enc, accp, Zp);
  k_stats<<<256, 256, 0, stream>>>(accp, Zp, out, gsum, gsumsq);
  k_bnelu<<<8192, 256, 0, stream>>>(out, gsum, gsumsq, gamma, beta);
}

// Round 6
// 168.000 us; speedup vs baseline: 1.1481x; 1.0552x over previous
//
#include <hip/hip_runtime.h>
#include <stdint.h>

#define ALPHA 0.2f
#define LOG2E 1.4426950408889634f

typedef __attribute__((ext_vector_type(8))) short short8;
typedef __attribute__((ext_vector_type(4))) float f32x4;
typedef __attribute__((ext_vector_type(16))) float f32x16;
typedef __attribute__((ext_vector_type(4))) int int4v;
typedef __attribute__((ext_vector_type(2))) unsigned int uint2v;

#if __has_builtin(__builtin_amdgcn_exp2f)
#define EXP2(x) __builtin_amdgcn_exp2f(x)
#else
#define EXP2(x) exp2f(x)
#endif

__device__ __forceinline__ unsigned short f2bf(float x){
  union { float f; uint32_t u; } v; v.f = x;
  uint32_t u = v.u;
  u += 0x7FFFu + ((u >> 16) & 1u);
  return (unsigned short)(u >> 16);
}
__device__ __forceinline__ float bf2f(unsigned short s){
  union { uint32_t u; float f; } v; v.u = ((uint32_t)s) << 16; return v.f;
}
// RNE pack of 2 f32 -> 2 bf16 in one instr
__device__ __forceinline__ unsigned cvt_pk_bf16(float lo, float hi){
  unsigned r;
  asm("v_cvt_pk_bf16_f32 %0, %1, %2" : "=v"(r) : "v"(lo), "v"(hi));
  return r;
}
// order-preserving f32 <-> u32 (for atomicMax); 0 is below every real encoding
__device__ __forceinline__ unsigned encf(float x){
  unsigned u = __float_as_uint(x);
  return (u & 0x80000000u) ? ~u : (u | 0x80000000u);
}
__device__ __forceinline__ float decf(unsigned u){
  return (u & 0x80000000u) ? __uint_as_float(u & 0x7FFFFFFFu) : __uint_as_float(~u);
}

// ---- hamilton^T as bf16 hi/lo planes + zero the tiny accumulators ----
__global__ void k_ham(const float* __restrict__ W, unsigned short* __restrict__ hi,
                      unsigned short* __restrict__ lo, unsigned* __restrict__ S2enc,
                      float* __restrict__ gsum, float* __restrict__ gsumsq){
  if (blockIdx.x == 0){
    if (threadIdx.x == 0) S2enc[0] = 0u;
    gsum[threadIdx.x] = 0.f; gsumsq[threadIdx.x] = 0.f;
  }
  int id = blockIdx.x * 256 + threadIdx.x;   // id = c*1024 + k
  int c = id >> 10, k = id & 1023;
  int b = k >> 8, r = k & 255;
  int cb = c >> 6, col = c & 63;
  const int   comp[4][4] = {{0,1,2,3},{1,0,3,2},{2,3,0,1},{3,2,1,0}};
  const float sgn [4][4] = {{1.f,-1.f,-1.f,-1.f},{1.f,1.f,-1.f,1.f},
                            {1.f,1.f,1.f,-1.f},{1.f,-1.f,1.f,1.f}};
  float v = sgn[b][cb] * W[r * 256 + comp[b][cb] * 64 + col];
  unsigned short h = f2bf(v);
  hi[id] = h;
  lo[id] = f2bf(v - bf2f(h));
}

// ---- fused: blocks 0..255 = GEMM1 (h = input@hamilton, fp32-split);
//             blocks 256..16639 = adj bitmask pack (independent -> overlaps) ----
// pack layout: word[(j>>10)*16 + ((j>>8)&3)*4 + (j&3)], bit ((j>>2)&63)
// hTt layout (tiled): hTt[(j>>3)*2048 + c*8 + (j&7)]
__global__ __launch_bounds__(256) void k_work(
    const float* __restrict__ inp, const int* __restrict__ adj,
    const unsigned short* __restrict__ hamHi, const unsigned short* __restrict__ hamLo,
    const float* __restrict__ avec, unsigned short* __restrict__ hTt,
    float* __restrict__ s1s, float* __restrict__ s2s, unsigned* __restrict__ S2enc,
    unsigned long long* __restrict__ bm){
  if (blockIdx.x >= 256){
    // ---------------- pack body (streams adj at full BW) ----------------
    const int lane = threadIdx.x & 63;
    const size_t wid = ((size_t)(blockIdx.x - 256) * 256 + threadIdx.x) >> 6;
    const size_t W0 = wid * 1024;              // 1024 consecutive elems per wave
    unsigned long long b[16];
#pragma unroll
    for (int q = 0; q < 4; ++q){
      int4v a = *(const int4v*)(adj + W0 + 256*q + 4*lane);
#pragma unroll
      for (int k = 0; k < 4; ++k) b[4*q + k] = __ballot(a[k] > 0);
    }
    if (lane < 16){
      unsigned long long v = b[0];
#pragma unroll
      for (int m = 1; m < 16; ++m) v = (lane == m) ? b[m] : v;
      bm[W0/64 + lane] = v;
    }
    return;
  }
  // ---------------- gemm1 body ----------------
  int i0 = blockIdx.x * 32;
  int w = threadIdx.x >> 6, lane = threadIdx.x & 63;
  int mi = lane & 15, g = lane >> 4;
  int cbase = w * 64;
  f32x4 acc[2][4];
#pragma unroll
  for (int mf=0; mf<2; ++mf)
#pragma unroll
    for (int nf=0; nf<4; ++nf) acc[mf][nf] = (f32x4){0.f,0.f,0.f,0.f};

  for (int k0 = 0; k0 < 1024; k0 += 32){
    short8 ah[2], al[2];
#pragma unroll
    for (int mf=0; mf<2; ++mf){
      const float* ap = inp + (size_t)(i0 + 16*mf + mi) * 1024 + k0 + 8*g;
      f32x4 x0 = *(const f32x4*)ap;
      f32x4 x1 = *(const f32x4*)(ap + 4);
#pragma unroll
      for (int e=0; e<8; ++e){
        float x = (e < 4) ? x0[e] : x1[e-4];
        unsigned short h = f2bf(x);
        ah[mf][e] = (short)h;
        al[mf][e] = (short)f2bf(x - bf2f(h));
      }
    }
    short8 bh[4], bl[4];
#pragma unroll
    for (int nf=0; nf<4; ++nf){
      size_t off = (size_t)(cbase + 16*nf + mi) * 1024 + k0 + 8*g;
      bh[nf] = *(const short8*)(hamHi + off);
      bl[nf] = *(const short8*)(hamLo + off);
    }
#pragma unroll
    for (int mf=0; mf<2; ++mf)
#pragma unroll
      for (int nf=0; nf<4; ++nf){
        acc[mf][nf] = __builtin_amdgcn_mfma_f32_16x16x32_bf16(ah[mf], bh[nf], acc[mf][nf], 0,0,0);
        acc[mf][nf] = __builtin_amdgcn_mfma_f32_16x16x32_bf16(ah[mf], bl[nf], acc[mf][nf], 0,0,0);
        acc[mf][nf] = __builtin_amdgcn_mfma_f32_16x16x32_bf16(al[mf], bh[nf], acc[mf][nf], 0,0,0);
      }
  }
  float p1[2][4] = {{0,0,0,0},{0,0,0,0}}, p2[2][4] = {{0,0,0,0},{0,0,0,0}};
#pragma unroll
  for (int nf=0; nf<4; ++nf){
    int c = cbase + 16*nf + mi;
    float a1c = avec[c], a2c = avec[256 + c];
#pragma unroll
    for (int mf=0; mf<2; ++mf){
      int jg = (i0 + 16*mf + 4*g) >> 3;        // j-group of the 4 rows
      uint2v u;
      u[0] = (uint32_t)f2bf(acc[mf][nf][0]) | ((uint32_t)f2bf(acc[mf][nf][1]) << 16);
      u[1] = (uint32_t)f2bf(acc[mf][nf][2]) | ((uint32_t)f2bf(acc[mf][nf][3]) << 16);
      *(uint2v*)(hTt + (size_t)jg * 2048 + c * 8 + (g & 1) * 4) = u;
#pragma unroll
      for (int rg=0; rg<4; ++rg){
        p1[mf][rg] += acc[mf][nf][rg] * a1c;
        p2[mf][rg] += acc[mf][nf][rg] * a2c;
      }
    }
  }
#pragma unroll
  for (int off=1; off<16; off<<=1){
#pragma unroll
    for (int mf=0; mf<2; ++mf)
#pragma unroll
      for (int rg=0; rg<4; ++rg){
        p1[mf][rg] += __shfl_xor(p1[mf][rg], off);
        p2[mf][rg] += __shfl_xor(p2[mf][rg], off);
      }
  }
  __shared__ float red1[4][32], red2[4][32];
  if (mi == 0){
#pragma unroll
    for (int mf=0; mf<2; ++mf)
#pragma unroll
      for (int rg=0; rg<4; ++rg){
        red1[w][16*mf + 4*g + rg] = p1[mf][rg];
        red2[w][16*mf + 4*g + rg] = p2[mf][rg];
      }
  }
  __syncthreads();
  if (threadIdx.x < 32){
    int r = threadIdx.x;
    float v1 = red1[0][r] + red1[1][r] + red1[2][r] + red1[3][r];
    float v2 = red2[0][r] + red2[1][r] + red2[2][r] + red2[3][r];
    s1s[i0 + r] = v1 * LOG2E;
    float v2s = v2 * LOG2E;
    s2s[i0 + r] = v2s;
    float m = v2s;
#pragma unroll
    for (int off=1; off<32; off<<=1) m = fmaxf(m, __shfl_xor(m, off));
    if (r == 0) atomicMax(S2enc, encf(m));
  }
}

// stage hT tile t (32KB, fully LINEAR in tiled layout) into hbuf[b]
#define STAGE(t, b) do { \
    const unsigned short* sp_ = hTt + (size_t)jw0 * 256 + (size_t)(t) * 16384; \
    _Pragma("unroll") \
    for (int r_ = 0; r_ < 8; ++r_){ \
      int ch_ = tid + r_*256; \
      __builtin_amdgcn_global_load_lds((const __attribute__((address_space(1))) void*)(const void*)(sp_ + ch_*8), \
          (__attribute__((address_space(3))) void*)(void*)&hbuf[(b)][ch_*8], 16, 0, 0); \
    } } while(0)

// ---- fused masked-softmax @ h : bm-masked, 32x32x16 MFMA, 2 blocks/CU ----
__global__ __launch_bounds__(256,2) void k_attn(
    const unsigned long long* __restrict__ bm, const unsigned short* __restrict__ hTt,
    const float* __restrict__ s1s, const float* __restrict__ s2s,
    const unsigned* __restrict__ S2enc, float* __restrict__ accp, float* __restrict__ Zp){
  __shared__ unsigned short hbuf[2][256*64];   // 64 KB double-buffered tiles (tiled layout)
  __shared__ float s2l[1024];                  // 4 KB s2 slice
  const int tid = threadIdx.x;
  const int id = blockIdx.x;
  // XCD swizzle: js = xcd -> each XCD keeps its 0.5MB hTt + 1MB bm slice L2-hot
  const int js = id & 7;
  const int rb = id >> 3;                      // 0..63
  const int w = tid >> 6, lane = tid & 63;
  const int r31 = lane & 31, hi = lane >> 5;
  const int i0w = rb * 128 + w * 32;           // wave owns 32 rows
  const int jw0 = js * 1024;

  { f32x4 v = *(const f32x4*)(s2s + jw0 + tid*4); *(f32x4*)&s2l[tid*4] = v; }

  const float S2MAX = decf(S2enc[0]);
  const float s1v = s1s[i0w + r31];
  const float xm = s1v + S2MAX;
  const float m2 = fmaxf(xm, ALPHA * xm);      // scaled lrelu of the global bound
  const float P1 = s1v - m2;
  const float P2 = ALPHA * s1v - m2;

  // bm words for this row & js slice: 16 words, 4 per group of 4 tiles
  const unsigned long long* brow = bm + (size_t)(i0w + r31) * 128 + js * 16;

  f32x16 acc[8];
#pragma unroll
  for (int nf=0; nf<8; ++nf)
#pragma unroll
    for (int q=0; q<16; ++q) acc[nf][q] = 0.f;
  float zac = 0.f;

  unsigned long long Wc[4], Wn[4];
#pragma unroll
  for (int k=0;k<4;++k) Wc[k] = brow[k];
  STAGE(0, 0);
  __syncthreads();

  for (int tile = 0; tile < 16; ++tile){
    const int buf = tile & 1;
    if ((tile & 3) == 0){
      if (tile){
#pragma unroll
        for (int k=0;k<4;++k) Wc[k] = Wn[k];
      }
      if (tile + 4 < 16){
        const unsigned long long* p = brow + (tile >> 2)*4 + 4;
#pragma unroll
        for (int k=0;k<4;++k) Wn[k] = p[k];
      }
    }
    if (tile < 15) STAGE(tile + 1, buf ^ 1);
#pragma unroll
    for (int ks=0; ks<4; ++ks){
      f32x4 sa = *(const f32x4*)&s2l[tile*64 + ks*16 + hi*8];
      f32x4 sb = *(const f32x4*)&s2l[tile*64 + ks*16 + hi*8 + 4];
      const int sh0 = ((tile & 3) << 4) + (ks << 2) + (hi << 1);
      unsigned tt[4];
#pragma unroll
      for (int k=0;k<4;++k) tt[k] = (unsigned)(Wc[k] >> sh0);
      float pe[8];
#pragma unroll
      for (int e=0; e<8; ++e){
        float s2e = (e < 4) ? sa[e] : sb[e-4];
        float t1 = P1 + s2e;
        float t2 = fmaf(ALPHA, s2e, P2);
        float p = EXP2(fmaxf(t1, t2));
        p = ((tt[e & 3] >> (e >> 2)) & 1u) ? p : 0.f;
        zac += p;
        pe[e] = p;
      }
      union { short8 s; unsigned u[4]; } pa;
#pragma unroll
      for (int wd=0; wd<4; ++wd) pa.u[wd] = cvt_pk_bf16(pe[2*wd], pe[2*wd+1]);
      // tiled LDS: jgroup = 2ks+hi, contiguous 16B per lane -> conflict-free
      const int jbase = (2*ks + hi) * 2048;
#pragma unroll
      for (int nf=0; nf<8; ++nf){
        short8 b = *(const short8*)&hbuf[buf][jbase + (32*nf + r31)*8];
        acc[nf] = __builtin_amdgcn_mfma_f32_32x32x16_bf16(pa.s, b, acc[nf], 0,0,0);
      }
    }
    __syncthreads();
  }
  // Z: combine the two j-halves (hi lanes) -> one slot per row
  zac += __shfl_xor(zac, 32);
  if (lane < 32) Zp[js*8192 + i0w + lane] = zac;
  // unnormalized h' partial: unique (js,row,c) slots, plain stores
#pragma unroll
  for (int nf=0; nf<8; ++nf){
    const int c = 32*nf + r31;
#pragma unroll
    for (int reg=0; reg<16; ++reg){
      const int roff = (reg&3) + 8*(reg>>2) + 4*hi;
      accp[(size_t)(js*8192 + i0w + roff)*256 + c] = acc[nf][reg];
    }
  }
}

// ---- reduce 8 partials, normalize by Z, write h', accumulate column stats ----
__global__ void k_stats(const float* __restrict__ accp, const float* __restrict__ Zp,
                        float* __restrict__ hp, float* __restrict__ gsum,
                        float* __restrict__ gsumsq){
  int c = threadIdx.x;
  int r0 = blockIdx.x * 32;
  float s = 0.f, sq = 0.f;
  for (int r=0; r<32; ++r){
    int i = r0 + r;
    float z = 0.f;
#pragma unroll
    for (int s8=0; s8<8; ++s8) z += Zp[s8*8192 + i];
    float inv = (z > 0.f) ? 1.f / z : 0.f;
    size_t o = (size_t)i * 256 + c;
    float v = 0.f;
#pragma unroll
    for (int s8=0; s8<8; ++s8) v += accp[o + (size_t)s8*8192*256];
    v *= inv;
    hp[o] = v;
    s += v; sq += v*v;
  }
  atomicAdd(&gsum[c], s);
  atomicAdd(&gsumsq[c], sq);
}

// ---- batchnorm + elu, in-place on d_out ----
__global__ void k_bnelu(float* __restrict__ out, const float* __restrict__ gsum,
                        const float* __restrict__ gsumsq, const float* __restrict__ gamma,
                        const float* __restrict__ beta){
  int id = blockIdx.x * 256 + threadIdx.x;
  int c = id & 255;
  float mean = gsum[c] * (1.f/8192.f);
  float var  = gsumsq[c] * (1.f/8192.f) - mean*mean;
  float x = (out[id] - mean) * rsqrtf(var + 1e-5f) * gamma[c] + beta[c];
  out[id] = x > 0.f ? x : (EXP2(x * LOG2E) - 1.f);
}

extern "C" void kernel_launch(void* const* d_in, const int* in_sizes, int n_in,
                              void* d_out, int out_size, void* d_ws, size_t ws_size,
                              hipStream_t stream){
  const float* inp   = (const float*)d_in[0];
  const int*   adj   = (const int*)d_in[1];
  const float* W     = (const float*)d_in[2];
  const float* avec  = (const float*)d_in[3];
  const float* gamma = (const float*)d_in[4];
  const float* beta  = (const float*)d_in[5];
  float* out = (float*)d_out;

  char* ws = (char*)d_ws;
  float* accp = (float*)ws;                               // 8*8192*256 f = 67 MB
  float* Zp   = accp + (size_t)8*8192*256;                // 65536 f
  unsigned short* hamHi = (unsigned short*)(Zp + 65536);  // 262144 bf16
  unsigned short* hamLo = hamHi + 262144;
  unsigned short* hTt   = hamLo + 262144;                 // 2097152 bf16 (tiled)
  float* s1s = (float*)(hTt + 2097152);
  float* s2s = s1s + 8192;
  unsigned* S2enc = (unsigned*)(s2s + 8192);
  float* gsum   = (float*)(S2enc + 64);
  float* gsumsq = gsum + 256;
  unsigned long long* bm = (unsigned long long*)(gsumsq + 256);  // 1M u64 = 8MB

  k_ham<<<1024, 256, 0, stream>>>(W, hamHi, hamLo, S2enc, gsum, gsumsq);
  k_work<<<16640, 256, 0, stream>>>(inp, adj, hamHi, hamLo, avec, hTt, s1s, s2s, S2enc, bm);
  k_attn<<<512, 256, 0, stream>>>(bm, hTt, s1s, s2s, S2enc, accp, Zp);
  k_stats<<<256, 256, 0, stream>>>(accp, Zp, out, gsum, gsumsq);
  k_bnelu<<<8192, 256, 0, stream>>>(out, gsum, gsumsq, gamma, beta);
}